// Round 7
// baseline (1781.002 us; speedup 1.0000x reference)
//
#include <hip/hip_runtime.h>
#include <hip/hip_bf16.h>
#include <math.h>

// B=2 T=1024 HID=2048 H=16 D=128 DV=128 R=4 CONV=4
// R14: scan v7 = 2 columns per wave (G=64 lanes over d, S = 4 regs).
// Shared k/q/dec/beta loads + converts amortize over 2 columns; the two
// independent DPP reduce ladders per micro-step interleave (ILP hides the
// serial chain). 512 blocks x 256 thr = 2048 waves = 2 waves/SIMD.
// Ladder/readlane/lane-63 store byte-identical to R11-validated pieces;
// XCD-clustered bijective remap re-derived for 512 blocks.
// GEMM/conv/norm kernels byte-identical R13 (1760us validated).

typedef unsigned short ushort_t;
typedef __attribute__((ext_vector_type(8))) short bf16x8;
typedef __attribute__((ext_vector_type(4))) float f32x4;
typedef __attribute__((ext_vector_type(8))) unsigned short u16x8;

__device__ __forceinline__ unsigned short f2bf(float f) {
  unsigned u = __float_as_uint(f);
  unsigned r = (u + 0x7FFFu + ((u >> 16) & 1u)) >> 16;  // RNE
  return (unsigned short)r;
}
// HW packed fp32->bf16 (RNE), lo in [15:0], hi in [31:16].
__device__ __forceinline__ unsigned f2bf_pk(float lo, float hi) {
  unsigned r;
  asm("v_cvt_pk_bf16_f32 %0, %1, %2" : "=v"(r) : "v"(lo), "v"(hi));
  return r;
}
__device__ __forceinline__ float bf2f(unsigned short u) {
  return __uint_as_float(((unsigned)u) << 16);
}
__device__ __forceinline__ float sigmoidf(float x) { return 1.f / (1.f + expf(-x)); }
__device__ __forceinline__ float softplusf(float x) {
  return (x > 20.f) ? x : log1pf(expf(x));
}
__device__ __forceinline__ void store1(float* p, float v) { *p = v; }
__device__ __forceinline__ void store1(unsigned short* p, float v) {
  *p = (unsigned short)f2bf_pk(v, v);
}

// Stage 1KB (64 lanes x 16B): per-lane global src, wave-uniform LDS base.
#if __has_builtin(__builtin_amdgcn_global_load_lds)
__device__ __forceinline__ void gload16(const void* g, void* lds, int lane) {
  (void)lane;
  __builtin_amdgcn_global_load_lds(
      (const __attribute__((address_space(1))) unsigned int*)g,
      (__attribute__((address_space(3))) unsigned int*)lds, 16, 0, 0);
}
#else
__device__ __forceinline__ void gload16(const void* g, void* lds, int lane) {
  uint4 v = *(const uint4*)g;
  *(uint4*)((char*)lds + lane * 16) = v;
}
#endif

// ---------------------------------------------------------------------------
// f32 -> bf16 convert, x8 per thread.
// ---------------------------------------------------------------------------
__global__ __launch_bounds__(256) void cvt_bf16_v8(const float* __restrict__ X,
                                                   unsigned short* __restrict__ Y,
                                                   int total8) {
  int i = blockIdx.x * 256 + threadIdx.x;
  if (i >= total8) return;
  const float4* s = (const float4*)(X + (size_t)i * 8);
  float4 a = s[0], b = s[1];
  *(uint4*)(Y + (size_t)i * 8) = make_uint4(f2bf_pk(a.x, a.y), f2bf_pk(a.z, a.w),
                                            f2bf_pk(b.x, b.y), f2bf_pk(b.z, b.w));
}

// ---------------------------------------------------------------------------
// bf16 NT GEMM — R13-validated. 128x128 tile, BK=64, gload_lds staging,
// XOR-swizzled 16B groups (g^row&7) on stage+read.
// ---------------------------------------------------------------------------
template <typename OutT>
__global__ __launch_bounds__(256) void gemm_bf16(const unsigned short* __restrict__ A,
                                                 const unsigned short* __restrict__ B,
                                                 OutT* __restrict__ Y,
                                                 int M, int N, int K) {
  __shared__ __attribute__((aligned(16))) unsigned short As[128 * 64];
  __shared__ __attribute__((aligned(16))) unsigned short Bs[128 * 64];
  const int tid = threadIdx.x;
  const int lane = tid & 63;
  const int wave = tid >> 6;
  const int quad = lane >> 4;
  const int l16 = lane & 15;
  const int wm = wave >> 1, wn = wave & 1;
  const int n0 = blockIdx.x * 128;
  const int m0 = blockIdx.y * 128;

  const int srow = lane >> 3;                 // 0..7 within an issue
  const int glog = (lane & 7) ^ (srow & 7);   // pre-swizzled source group
  const unsigned short* Ab = A + (size_t)(m0 + wave * 32 + srow) * K + glog * 8;
  const unsigned short* Bb = B + (size_t)(n0 + wave * 32 + srow) * K + glog * 8;
  unsigned short* AsW = As + wave * 2048;     // 4KB per wave
  unsigned short* BsW = Bs + wave * 2048;

  f32x4 acc[4][4];
#pragma unroll
  for (int i = 0; i < 4; ++i)
#pragma unroll
    for (int j = 0; j < 4; ++j) acc[i][j] = (f32x4){0.f, 0.f, 0.f, 0.f};

  for (int k0 = 0; k0 < K; k0 += 64) {
    __syncthreads();
#pragma unroll
    for (int r = 0; r < 4; ++r) {
      gload16(Ab + (size_t)(r * 8) * K + k0, AsW + r * 512, lane);
      gload16(Bb + (size_t)(r * 8) * K + k0, BsW + r * 512, lane);
    }
    __syncthreads();
#pragma unroll
    for (int kk = 0; kk < 2; ++kk) {
      bf16x8 av[4], bv[4];
#pragma unroll
      for (int i = 0; i < 4; ++i) {
        int row = wm * 64 + i * 16 + l16;
        av[i] = *(const bf16x8*)&As[row * 64 + (((kk * 4 + quad) ^ (row & 7)) * 8)];
      }
#pragma unroll
      for (int j = 0; j < 4; ++j) {
        int row = wn * 64 + j * 16 + l16;
        bv[j] = *(const bf16x8*)&Bs[row * 64 + (((kk * 4 + quad) ^ (row & 7)) * 8)];
      }
#pragma unroll
      for (int i = 0; i < 4; ++i)
#pragma unroll
        for (int j = 0; j < 4; ++j)
          acc[i][j] = __builtin_amdgcn_mfma_f32_16x16x32_bf16(av[i], bv[j], acc[i][j], 0, 0, 0);
    }
  }

#pragma unroll
  for (int i = 0; i < 4; ++i)
#pragma unroll
    for (int j = 0; j < 4; ++j) {
      int rr = m0 + wm * 64 + i * 16 + quad * 4;
      int cc = n0 + wn * 64 + j * 16 + l16;
#pragma unroll
      for (int r = 0; r < 4; ++r)
        store1(Y + (size_t)(rr + r) * N + cc, acc[i][j][r]);
    }
}

// ---------------------------------------------------------------------------
// MFMA GEMM (NT) with f32 inputs — R11-validated; kept for the small GEMMs.
// ---------------------------------------------------------------------------
template <typename OutT>
__global__ __launch_bounds__(256) void gemm_mfma(const float* __restrict__ A,
                                                 const float* __restrict__ B,
                                                 OutT* __restrict__ Y,
                                                 int M, int N, int K) {
  __shared__ __attribute__((aligned(16))) unsigned short As[128 * 40];
  __shared__ __attribute__((aligned(16))) unsigned short Bs[128 * 40];
  const int tid = threadIdx.x;
  const int lane = tid & 63;
  const int wave = tid >> 6;
  const int quad = lane >> 4;
  const int l16 = lane & 15;
  const int wm = wave >> 1;   // 0..1
  const int wn = wave & 1;    // 0..1
  const int n0 = blockIdx.x * 128;
  const int m0 = blockIdx.y * 128;

  f32x4 acc[4][4];
#pragma unroll
  for (int i = 0; i < 4; ++i)
#pragma unroll
    for (int j = 0; j < 4; ++j) acc[i][j] = (f32x4){0.f, 0.f, 0.f, 0.f};

  for (int k0 = 0; k0 < K; k0 += 32) {
    __syncthreads();
#pragma unroll
    for (int u = tid; u < 512; u += 256) {
      int m = u >> 2, c = u & 3;
      const float* src = A + (size_t)(m0 + m) * K + k0 + c * 8;
      float4 a0 = *(const float4*)(src);
      float4 a1 = *(const float4*)(src + 4);
      *(uint2*)&As[m * 40 + c * 8] =
          make_uint2(f2bf_pk(a0.x, a0.y), f2bf_pk(a0.z, a0.w));
      *(uint2*)&As[m * 40 + c * 8 + 4] =
          make_uint2(f2bf_pk(a1.x, a1.y), f2bf_pk(a1.z, a1.w));
    }
#pragma unroll
    for (int u = tid; u < 512; u += 256) {
      int n = u >> 2, c = u & 3;
      float4 b0 = make_float4(0.f, 0.f, 0.f, 0.f);
      float4 b1 = b0;
      if (n0 + n < N) {
        const float* src = B + (size_t)(n0 + n) * K + k0 + c * 8;
        b0 = *(const float4*)(src);
        b1 = *(const float4*)(src + 4);
      }
      *(uint2*)&Bs[n * 40 + c * 8] =
          make_uint2(f2bf_pk(b0.x, b0.y), f2bf_pk(b0.z, b0.w));
      *(uint2*)&Bs[n * 40 + c * 8 + 4] =
          make_uint2(f2bf_pk(b1.x, b1.y), f2bf_pk(b1.z, b1.w));
    }
    __syncthreads();

    bf16x8 av[4], bv[4];
#pragma unroll
    for (int i = 0; i < 4; ++i)
      av[i] = *(const bf16x8*)&As[(wm * 64 + i * 16 + l16) * 40 + quad * 8];
#pragma unroll
    for (int j = 0; j < 4; ++j)
      bv[j] = *(const bf16x8*)&Bs[(wn * 64 + j * 16 + l16) * 40 + quad * 8];
#pragma unroll
    for (int i = 0; i < 4; ++i)
#pragma unroll
      for (int j = 0; j < 4; ++j)
        acc[i][j] = __builtin_amdgcn_mfma_f32_16x16x32_bf16(av[i], bv[j], acc[i][j], 0, 0, 0);
  }

#pragma unroll
  for (int i = 0; i < 4; ++i)
#pragma unroll
    for (int j = 0; j < 4; ++j) {
      int rr = m0 + wm * 64 + i * 16 + quad * 4;
      int cc = n0 + wn * 64 + j * 16 + l16;
      if (cc < N) {
#pragma unroll
        for (int r = 0; r < 4; ++r)
          store1(Y + (size_t)(rr + r) * N + cc, acc[i][j][r]);
      }
    }
}

// ---------------------------------------------------------------------------
// Depthwise causal conv (K=4) + silu — vectorized x8 (ushort8), cvt_pk out.
// ---------------------------------------------------------------------------
__global__ __launch_bounds__(256) void conv_silu_v8(const unsigned short* __restrict__ X,
                                                    const float* __restrict__ Wc,
                                                    unsigned short* __restrict__ Y,
                                                    int C, int total8) {
  int i8 = blockIdx.x * 256 + threadIdx.x;
  if (i8 >= total8) return;
  int idx = i8 * 8;
  int c = idx % C;
  int m = idx / C;
  int t = m & 1023;
  u16x8 x0 = *(const u16x8*)(X + idx);
  u16x8 x1 = (u16x8)(unsigned short)0;
  u16x8 x2 = x1, x3 = x1;
  if (t >= 1) x1 = *(const u16x8*)(X + idx - C);
  if (t >= 2) x2 = *(const u16x8*)(X + idx - 2 * C);
  if (t >= 3) x3 = *(const u16x8*)(X + idx - 3 * C);
  float r[8];
#pragma unroll
  for (int e = 0; e < 8; ++e) {
    float4 w4 = *(const float4*)(Wc + (size_t)(c + e) * 4);
    float acc = w4.w * bf2f(x0[e]);
    acc = fmaf(w4.z, bf2f(x1[e]), acc);
    acc = fmaf(w4.y, bf2f(x2[e]), acc);
    acc = fmaf(w4.x, bf2f(x3[e]), acc);
    r[e] = acc * sigmoidf(acc);
  }
  *(uint4*)(Y + idx) = make_uint4(f2bf_pk(r[0], r[1]), f2bf_pk(r[2], r[3]),
                                  f2bf_pk(r[4], r[5]), f2bf_pk(r[6], r[7]));
}

// ---------------------------------------------------------------------------
// l2norm rows of 128 (bf16, in-place) — R6-validated.
// ---------------------------------------------------------------------------
__global__ __launch_bounds__(256) void l2norm_bf16(unsigned short* __restrict__ X,
                                                   int rows, float post) {
  int row = blockIdx.x * 4 + (threadIdx.x >> 6);
  int lane = threadIdx.x & 63;
  if (row >= rows) return;
  unsigned short* p = X + (size_t)row * 128;
  float a = bf2f(p[lane]), b = bf2f(p[lane + 64]);
  float ss = fmaf(a, a, b * b);
#pragma unroll
  for (int m = 32; m; m >>= 1) ss += __shfl_xor(ss, m);
  float sc = rsqrtf(ss + 1e-6f) * post;
  p[lane] = f2bf(a * sc);
  p[lane + 64] = f2bf(b * sc);
}

// ---------------------------------------------------------------------------
// decay in-place (R6-validated).
// ---------------------------------------------------------------------------
__global__ __launch_bounds__(256) void decay_ip(float* __restrict__ G,
                                                const float* __restrict__ alog,
                                                const float* __restrict__ dtb,
                                                int total) {
  int idx = blockIdx.x * 256 + threadIdx.x;
  if (idx >= total) return;
  int n = idx & 2047;
  float A = expf(alog[n >> 7]);
  float x = G[idx] + dtb[n];
  G[idx] = expf(-A * softplusf(x));
}

__global__ __launch_bounds__(256) void sigmoid_ip(float* __restrict__ G, int total) {
  int idx = blockIdx.x * 256 + threadIdx.x;
  if (idx < total) G[idx] = sigmoidf(G[idx]);
}

// ---------------------------------------------------------------------------
// Recurrent scan v7 — 2 columns per wave, 64 lanes over d=128 (2 d/lane),
// S = {SA0,SA1,SB0,SB1}. Shared k/q/dec/beta; two independent DPP ladders
// per micro-step interleave for ILP. 512 blocks x 256 thr = 2048 waves.
// Ladder (R11-validated): xor1(0xB1), xor2(0x4E), half_mirror(0x141),
// mirror(0x140), bcast15(0x142), bcast31(0x143) -> lane 63 total;
// u via readlane(63); o stored as float2 from lane 63.
// ---------------------------------------------------------------------------
template <int CTRL>
__device__ __forceinline__ float dppadd(float x) {
  int y = __builtin_amdgcn_update_dpp(0, __float_as_int(x), CTRL, 0xF, 0xF, true);
  return x + __int_as_float(y);
}
__device__ __forceinline__ float red64_l63(float x) {
  x = dppadd<0xB1>(x);
  x = dppadd<0x4E>(x);
  x = dppadd<0x141>(x);
  x = dppadd<0x140>(x);
  x = dppadd<0x142>(x);
  x = dppadd<0x143>(x);
  return x;  // lane 63 holds the 64-lane total
}
__device__ __forceinline__ float rdl63(float x) {
  return __int_as_float(__builtin_amdgcn_readlane(__float_as_int(x), 63));
}

struct Pref2 {
  ushort2 k[4];   // k[j] at d0, d0+1 (shared across both columns)
  ushort2 q;      // q at d0, d0+1
  float2 d;       // dec at d0, d0+1
  float4 beta;    // 4 micro-steps
  ushort2 v[4];   // v[j] at colA, colA+1
};

__global__ __launch_bounds__(256) void scan_kernel7(
    const unsigned short* __restrict__ Qn, const unsigned short* __restrict__ Kn,
    const unsigned short* __restrict__ Vb, const float* __restrict__ Dec,
    const float* __restrict__ BetaS, const float* __restrict__ ml,
    const float* __restrict__ alog, const float* __restrict__ dtb,
    float* __restrict__ O) {
  // Bijective XCD-clustering for 512 blocks: all 16 cq-blocks of one (b,h)
  // share orig%8 -> one XCD's L2.
  const int orig = blockIdx.x;       // 0..511
  const int xcd = orig & 7;
  const int rr = orig >> 3;          // 0..63
  const int bh = xcd * 4 + (rr & 3); // 0..31
  const int cq = rr >> 2;            // 0..15
  const int h = bh & 15;
  const int b = bh >> 4;
  const int wave = threadIdx.x >> 6; // 0..3
  const int lane = threadIdx.x & 63;
  const int colA = cq * 8 + wave * 2;  // even; wave owns columns colA, colA+1
  const int d0 = lane * 2;

  const float A = expf(alog[h]);
  const float df0 = expf(-A * softplusf(-10000.f + dtb[h * 128 + d0]));
  const float df1 = expf(-A * softplusf(-10000.f + dtb[h * 128 + d0 + 1]));

  float wj[4];
  {
    float l0 = ml[h * 4 + 0], l1 = ml[h * 4 + 1];
    float l2 = ml[h * 4 + 2], l3 = ml[h * 4 + 3];
    float mx = fmaxf(fmaxf(l0, l1), fmaxf(l2, l3));
    float e0 = expf(l0 - mx), e1 = expf(l1 - mx);
    float e2 = expf(l2 - mx), e3 = expf(l3 - mx);
    float inv = 1.f / (e0 + e1 + e2 + e3);
    wj[0] = e0 * inv; wj[1] = e1 * inv; wj[2] = e2 * inv; wj[3] = e3 * inv;
  }

  float SA0 = 0.f, SA1 = 0.f, SB0 = 0.f, SB1 = 0.f;

  auto LD = [&](int t, Pref2& P) {
    const size_t base = ((size_t)(b * 1024 + t) * 16 + h);
    const unsigned short* kp = Kn + base * 512 + d0;
    const unsigned short* vp = Vb + base * 512 + colA;
#pragma unroll
    for (int j = 0; j < 4; ++j) {
      P.k[j] = *(const ushort2*)(kp + j * 128);
      P.v[j] = *(const ushort2*)(vp + j * 128);
    }
    P.q = *(const ushort2*)(Qn + base * 128 + d0);
    P.d = *(const float2*)(Dec + base * 128 + d0);
    P.beta = *(const float4*)(BetaS + base * 4);
  };

  auto STEP = [&](const Pref2& P, int t) {
    const float qf0 = bf2f(P.q.x), qf1 = bf2f(P.q.y);
    float oA = 0.f, oB = 0.f;
    const float bc[4] = {P.beta.x, P.beta.y, P.beta.z, P.beta.w};
#pragma unroll
    for (int j = 0; j < 4; ++j) {
      const float kf0 = bf2f(P.k[j].x), kf1 = bf2f(P.k[j].y);
      const float dd0 = (j == 0) ? P.d.x : df0;
      const float dd1 = (j == 0) ? P.d.y : df1;
      SA0 *= dd0; SA1 *= dd1;
      SB0 *= dd0; SB1 *= dd1;
      float pA = fmaf(kf0, SA0, kf1 * SA1);
      float pB = fmaf(kf0, SB0, kf1 * SB1);
      pA = red64_l63(pA);       // two independent ladders -> ILP
      pB = red64_l63(pB);
      const float uA = rdl63(pA);
      const float uB = rdl63(pB);
      const float ccA = bc[j] * (bf2f(P.v[j].x) - uA);
      const float ccB = bc[j] * (bf2f(P.v[j].y) - uB);
      SA0 = fmaf(ccA, kf0, SA0); SA1 = fmaf(ccA, kf1, SA1);
      SB0 = fmaf(ccB, kf0, SB0); SB1 = fmaf(ccB, kf1, SB1);
      oA = fmaf(wj[j], fmaf(qf0, SA0, qf1 * SA1), oA);
      oB = fmaf(wj[j], fmaf(qf0, SB0, qf1 * SB1), oB);
    }
    oA = red64_l63(oA);
    oB = red64_l63(oB);
    if (lane == 63) {
      const size_t base = ((size_t)(b * 1024 + t) * 16 + h);
      *(float2*)(O + base * 128 + colA) = make_float2(oA, oB);
    }
  };

  Pref2 P0, P1;
  LD(0, P0);
  for (int t = 0; t < 1024; t += 2) {
    LD(t + 1, P1);
    STEP(P0, t);
    if (t + 2 < 1024) LD(t + 2, P0);
    STEP(P1, t + 1);
  }
}

// ---------------------------------------------------------------------------
// RMS-norm * o_norm_w * sigmoid(gate + g2_b), in-place on O(f32) — R6-validated.
// ---------------------------------------------------------------------------
__global__ __launch_bounds__(256) void norm_gate(float* __restrict__ O,
                                                 const unsigned short* __restrict__ G,
                                                 const float* __restrict__ g2b,
                                                 const float* __restrict__ onw,
                                                 int rows) {
  int row = blockIdx.x * 4 + (threadIdx.x >> 6);
  int lane = threadIdx.x & 63;
  if (row >= rows) return;
  float* p = O + (size_t)row * 128;
  int m = row >> 4, h = row & 15;
  const unsigned short* gp = G + (size_t)m * 2048 + h * 128;
  const float* gb = g2b + h * 128;
  float a = p[lane], bv = p[lane + 64];
  float ss = fmaf(a, a, bv * bv);
#pragma unroll
  for (int k = 32; k; k >>= 1) ss += __shfl_xor(ss, k);
  float sc = rsqrtf(ss * (1.f / 128.f) + 1e-5f);
  float ga = sigmoidf(bf2f(gp[lane]) + gb[lane]);
  float gbv = sigmoidf(bf2f(gp[lane + 64]) + gb[lane + 64]);
  p[lane] = a * sc * onw[lane] * ga;
  p[lane + 64] = bv * sc * onw[lane + 64] * gbv;
}

// ---------------------------------------------------------------------------
extern "C" void kernel_launch(void* const* d_in, const int* in_sizes, int n_in,
                              void* d_out, int out_size, void* d_ws, size_t ws_size,
                              hipStream_t stream) {
  const float* x    = (const float*)d_in[0];
  const float* qw   = (const float*)d_in[1];
  const float* kw   = (const float*)d_in[2];
  const float* vw   = (const float*)d_in[3];
  const float* qcw  = (const float*)d_in[4];
  const float* kcw  = (const float*)d_in[5];
  const float* vcw  = (const float*)d_in[6];
  const float* f1w  = (const float*)d_in[7];
  const float* f2w  = (const float*)d_in[8];
  const float* bw   = (const float*)d_in[9];
  const float* ml   = (const float*)d_in[10];
  const float* alog = (const float*)d_in[11];
  const float* dtb  = (const float*)d_in[12];
  const float* g1w  = (const float*)d_in[13];
  const float* g2w  = (const float*)d_in[14];
  const float* g2b  = (const float*)d_in[15];
  const float* onw  = (const float*)d_in[16];
  const float* ow   = (const float*)d_in[17];
  float* out = (float*)d_out;  // fp32 output

  // workspace carve — peak 120 MiB (R13-validated layout).
  char* w8 = (char*)d_ws;
  unsigned short* P    = (unsigned short*)(w8);               // [0, 32M)
  float*          dec  = (float*)(w8);                        // [0, 16M)
  unsigned short* gate = (unsigned short*)(w8 + 16777216);    // 8 MB
  float*          beta = (float*)(w8 + 25165824);             // 512 KB
  float*          g1t  = (float*)(w8 + 25690112);             // 1 MB
  unsigned short* Kc   = (unsigned short*)(w8 + 33554432);    // 32 MB
  unsigned short* Vc   = (unsigned short*)(w8 + 67108864);    // 32 MB
  unsigned short* wbig = (unsigned short*)(w8 + 67108864);    // kwbf/vwbf (32 MB)
  unsigned short* Qc   = (unsigned short*)(w8 + 100663296);   // 8 MB
  unsigned short* xbf  = (unsigned short*)(w8 + 109051904);   // 8 MB
  unsigned short* qwbf = (unsigned short*)(w8 + 117440512);   // 8 MB (ends 120MiB)
  float*          o    = (float*)(w8 + 109051904);            // 16 MB (scan out)
  unsigned short* owbf = (unsigned short*)(w8);               // 8 MB (post-scan)
  unsigned short* obf  = (unsigned short*)(w8 + 8388608);     // 8 MB (post-scan)
  (void)ws_size;

  const int M = 2048;
  dim3 blk(256);

  // ---- convert x once (used by K/V/Q big GEMMs) ----
  cvt_bf16_v8<<<2048, blk, 0, stream>>>(x, xbf, 524288);

  // ---- phase 1: big projections (bf16 MFMA + gload_lds) + conv ----
  cvt_bf16_v8<<<8192, blk, 0, stream>>>(kw, wbig, 2097152);
  gemm_bf16<unsigned short><<<dim3(64, 16), blk, 0, stream>>>(xbf, wbig, P, M, 8192, 2048);
  conv_silu_v8<<<8192, blk, 0, stream>>>(P, kcw, Kc, 8192, 2097152);
  cvt_bf16_v8<<<8192, blk, 0, stream>>>(vw, wbig, 2097152);
  gemm_bf16<unsigned short><<<dim3(64, 16), blk, 0, stream>>>(xbf, wbig, P, M, 8192, 2048);
  conv_silu_v8<<<8192, blk, 0, stream>>>(P, vcw, Vc, 8192, 2097152);
  cvt_bf16_v8<<<2048, blk, 0, stream>>>(qw, qwbf, 524288);
  gemm_bf16<unsigned short><<<dim3(16, 16), blk, 0, stream>>>(xbf, qwbf, P, M, 2048, 2048);
  conv_silu_v8<<<2048, blk, 0, stream>>>(P, qcw, Qc, 2048, 524288);

  // ---- phase 2: small projections (f32 path; P region now dead) ----
  gemm_mfma<float><<<dim3(1, 16), blk, 0, stream>>>(x, f1w, g1t, M, 128, 2048);
  gemm_mfma<float><<<dim3(16, 16), blk, 0, stream>>>(g1t, f2w, dec, M, 2048, 128);
  decay_ip<<<16384, blk, 0, stream>>>(dec, alog, dtb, 4194304);

  gemm_mfma<float><<<dim3(1, 16), blk, 0, stream>>>(x, bw, beta, M, 64, 2048);
  sigmoid_ip<<<512, blk, 0, stream>>>(beta, 131072);

  gemm_mfma<float><<<dim3(1, 16), blk, 0, stream>>>(x, g1w, g1t, M, 128, 2048);
  gemm_mfma<unsigned short><<<dim3(16, 16), blk, 0, stream>>>(g1t, g2w, gate, M, 2048, 128);

  // ---- l2 norms (in-place bf16) ----
  l2norm_bf16<<<8192, blk, 0, stream>>>(Qc, 32768, 0.08838834764831845f);
  l2norm_bf16<<<32768, blk, 0, stream>>>(Kc, 131072, 1.0f);

  // ---- recurrent scan (2 cols/wave, dual-ladder ILP) ----
  scan_kernel7<<<512, dim3(256), 0, stream>>>(Qc, Kc, Vc, dec, beta, ml, alog, dtb, o);

  // ---- RMS-norm + gate ----
  norm_gate<<<8192, blk, 0, stream>>>(o, gate, g2b, onw, 32768);

  // ---- final projection (bf16 path) -> fp32 out ----
  cvt_bf16_v8<<<2048, blk, 0, stream>>>(o, obf, 524288);
  cvt_bf16_v8<<<2048, blk, 0, stream>>>(ow, owbf, 524288);
  gemm_bf16<float><<<dim3(16, 16), blk, 0, stream>>>(obf, owbf, out, M, 2048, 2048);
}

// Round 8
// 1647.433 us; speedup vs baseline: 1.0811x; 1.0811x over previous
//
#include <hip/hip_runtime.h>
#include <hip/hip_bf16.h>
#include <math.h>

// B=2 T=1024 HID=2048 H=16 D=128 DV=128 R=4 CONV=4
// R15: scan v8 = R14's 2-col/wave structure + prefetch depth 3 (4 named
// Pref2 buffers, hand-unrolled x4 loop, clamped tail loads). Diagnosis:
// R13/R14 both pinned at ~850ns/step because 1-step prefetch cover ==
// L2-miss latency (per-XCD working set 11MB > 4MB L2). Deeper cover
// removes the ~700cy/step residual stall. Ladder/readlane/lane-63 store
// byte-identical R11-validated. GEMM/conv/norm kernels byte-identical R13.

typedef unsigned short ushort_t;
typedef __attribute__((ext_vector_type(8))) short bf16x8;
typedef __attribute__((ext_vector_type(4))) float f32x4;
typedef __attribute__((ext_vector_type(8))) unsigned short u16x8;

__device__ __forceinline__ unsigned short f2bf(float f) {
  unsigned u = __float_as_uint(f);
  unsigned r = (u + 0x7FFFu + ((u >> 16) & 1u)) >> 16;  // RNE
  return (unsigned short)r;
}
// HW packed fp32->bf16 (RNE), lo in [15:0], hi in [31:16].
__device__ __forceinline__ unsigned f2bf_pk(float lo, float hi) {
  unsigned r;
  asm("v_cvt_pk_bf16_f32 %0, %1, %2" : "=v"(r) : "v"(lo), "v"(hi));
  return r;
}
__device__ __forceinline__ float bf2f(unsigned short u) {
  return __uint_as_float(((unsigned)u) << 16);
}
__device__ __forceinline__ float sigmoidf(float x) { return 1.f / (1.f + expf(-x)); }
__device__ __forceinline__ float softplusf(float x) {
  return (x > 20.f) ? x : log1pf(expf(x));
}
__device__ __forceinline__ void store1(float* p, float v) { *p = v; }
__device__ __forceinline__ void store1(unsigned short* p, float v) {
  *p = (unsigned short)f2bf_pk(v, v);
}

// Stage 1KB (64 lanes x 16B): per-lane global src, wave-uniform LDS base.
#if __has_builtin(__builtin_amdgcn_global_load_lds)
__device__ __forceinline__ void gload16(const void* g, void* lds, int lane) {
  (void)lane;
  __builtin_amdgcn_global_load_lds(
      (const __attribute__((address_space(1))) unsigned int*)g,
      (__attribute__((address_space(3))) unsigned int*)lds, 16, 0, 0);
}
#else
__device__ __forceinline__ void gload16(const void* g, void* lds, int lane) {
  uint4 v = *(const uint4*)g;
  *(uint4*)((char*)lds + lane * 16) = v;
}
#endif

// ---------------------------------------------------------------------------
// f32 -> bf16 convert, x8 per thread.
// ---------------------------------------------------------------------------
__global__ __launch_bounds__(256) void cvt_bf16_v8(const float* __restrict__ X,
                                                   unsigned short* __restrict__ Y,
                                                   int total8) {
  int i = blockIdx.x * 256 + threadIdx.x;
  if (i >= total8) return;
  const float4* s = (const float4*)(X + (size_t)i * 8);
  float4 a = s[0], b = s[1];
  *(uint4*)(Y + (size_t)i * 8) = make_uint4(f2bf_pk(a.x, a.y), f2bf_pk(a.z, a.w),
                                            f2bf_pk(b.x, b.y), f2bf_pk(b.z, b.w));
}

// ---------------------------------------------------------------------------
// bf16 NT GEMM — R13-validated. 128x128 tile, BK=64, gload_lds staging,
// XOR-swizzled 16B groups (g^row&7) on stage+read.
// ---------------------------------------------------------------------------
template <typename OutT>
__global__ __launch_bounds__(256) void gemm_bf16(const unsigned short* __restrict__ A,
                                                 const unsigned short* __restrict__ B,
                                                 OutT* __restrict__ Y,
                                                 int M, int N, int K) {
  __shared__ __attribute__((aligned(16))) unsigned short As[128 * 64];
  __shared__ __attribute__((aligned(16))) unsigned short Bs[128 * 64];
  const int tid = threadIdx.x;
  const int lane = tid & 63;
  const int wave = tid >> 6;
  const int quad = lane >> 4;
  const int l16 = lane & 15;
  const int wm = wave >> 1, wn = wave & 1;
  const int n0 = blockIdx.x * 128;
  const int m0 = blockIdx.y * 128;

  const int srow = lane >> 3;                 // 0..7 within an issue
  const int glog = (lane & 7) ^ (srow & 7);   // pre-swizzled source group
  const unsigned short* Ab = A + (size_t)(m0 + wave * 32 + srow) * K + glog * 8;
  const unsigned short* Bb = B + (size_t)(n0 + wave * 32 + srow) * K + glog * 8;
  unsigned short* AsW = As + wave * 2048;     // 4KB per wave
  unsigned short* BsW = Bs + wave * 2048;

  f32x4 acc[4][4];
#pragma unroll
  for (int i = 0; i < 4; ++i)
#pragma unroll
    for (int j = 0; j < 4; ++j) acc[i][j] = (f32x4){0.f, 0.f, 0.f, 0.f};

  for (int k0 = 0; k0 < K; k0 += 64) {
    __syncthreads();
#pragma unroll
    for (int r = 0; r < 4; ++r) {
      gload16(Ab + (size_t)(r * 8) * K + k0, AsW + r * 512, lane);
      gload16(Bb + (size_t)(r * 8) * K + k0, BsW + r * 512, lane);
    }
    __syncthreads();
#pragma unroll
    for (int kk = 0; kk < 2; ++kk) {
      bf16x8 av[4], bv[4];
#pragma unroll
      for (int i = 0; i < 4; ++i) {
        int row = wm * 64 + i * 16 + l16;
        av[i] = *(const bf16x8*)&As[row * 64 + (((kk * 4 + quad) ^ (row & 7)) * 8)];
      }
#pragma unroll
      for (int j = 0; j < 4; ++j) {
        int row = wn * 64 + j * 16 + l16;
        bv[j] = *(const bf16x8*)&Bs[row * 64 + (((kk * 4 + quad) ^ (row & 7)) * 8)];
      }
#pragma unroll
      for (int i = 0; i < 4; ++i)
#pragma unroll
        for (int j = 0; j < 4; ++j)
          acc[i][j] = __builtin_amdgcn_mfma_f32_16x16x32_bf16(av[i], bv[j], acc[i][j], 0, 0, 0);
    }
  }

#pragma unroll
  for (int i = 0; i < 4; ++i)
#pragma unroll
    for (int j = 0; j < 4; ++j) {
      int rr = m0 + wm * 64 + i * 16 + quad * 4;
      int cc = n0 + wn * 64 + j * 16 + l16;
#pragma unroll
      for (int r = 0; r < 4; ++r)
        store1(Y + (size_t)(rr + r) * N + cc, acc[i][j][r]);
    }
}

// ---------------------------------------------------------------------------
// MFMA GEMM (NT) with f32 inputs — R11-validated; kept for the small GEMMs.
// ---------------------------------------------------------------------------
template <typename OutT>
__global__ __launch_bounds__(256) void gemm_mfma(const float* __restrict__ A,
                                                 const float* __restrict__ B,
                                                 OutT* __restrict__ Y,
                                                 int M, int N, int K) {
  __shared__ __attribute__((aligned(16))) unsigned short As[128 * 40];
  __shared__ __attribute__((aligned(16))) unsigned short Bs[128 * 40];
  const int tid = threadIdx.x;
  const int lane = tid & 63;
  const int wave = tid >> 6;
  const int quad = lane >> 4;
  const int l16 = lane & 15;
  const int wm = wave >> 1;   // 0..1
  const int wn = wave & 1;    // 0..1
  const int n0 = blockIdx.x * 128;
  const int m0 = blockIdx.y * 128;

  f32x4 acc[4][4];
#pragma unroll
  for (int i = 0; i < 4; ++i)
#pragma unroll
    for (int j = 0; j < 4; ++j) acc[i][j] = (f32x4){0.f, 0.f, 0.f, 0.f};

  for (int k0 = 0; k0 < K; k0 += 32) {
    __syncthreads();
#pragma unroll
    for (int u = tid; u < 512; u += 256) {
      int m = u >> 2, c = u & 3;
      const float* src = A + (size_t)(m0 + m) * K + k0 + c * 8;
      float4 a0 = *(const float4*)(src);
      float4 a1 = *(const float4*)(src + 4);
      *(uint2*)&As[m * 40 + c * 8] =
          make_uint2(f2bf_pk(a0.x, a0.y), f2bf_pk(a0.z, a0.w));
      *(uint2*)&As[m * 40 + c * 8 + 4] =
          make_uint2(f2bf_pk(a1.x, a1.y), f2bf_pk(a1.z, a1.w));
    }
#pragma unroll
    for (int u = tid; u < 512; u += 256) {
      int n = u >> 2, c = u & 3;
      float4 b0 = make_float4(0.f, 0.f, 0.f, 0.f);
      float4 b1 = b0;
      if (n0 + n < N) {
        const float* src = B + (size_t)(n0 + n) * K + k0 + c * 8;
        b0 = *(const float4*)(src);
        b1 = *(const float4*)(src + 4);
      }
      *(uint2*)&Bs[n * 40 + c * 8] =
          make_uint2(f2bf_pk(b0.x, b0.y), f2bf_pk(b0.z, b0.w));
      *(uint2*)&Bs[n * 40 + c * 8 + 4] =
          make_uint2(f2bf_pk(b1.x, b1.y), f2bf_pk(b1.z, b1.w));
    }
    __syncthreads();

    bf16x8 av[4], bv[4];
#pragma unroll
    for (int i = 0; i < 4; ++i)
      av[i] = *(const bf16x8*)&As[(wm * 64 + i * 16 + l16) * 40 + quad * 8];
#pragma unroll
    for (int j = 0; j < 4; ++j)
      bv[j] = *(const bf16x8*)&Bs[(wn * 64 + j * 16 + l16) * 40 + quad * 8];
#pragma unroll
    for (int i = 0; i < 4; ++i)
#pragma unroll
      for (int j = 0; j < 4; ++j)
        acc[i][j] = __builtin_amdgcn_mfma_f32_16x16x32_bf16(av[i], bv[j], acc[i][j], 0, 0, 0);
  }

#pragma unroll
  for (int i = 0; i < 4; ++i)
#pragma unroll
    for (int j = 0; j < 4; ++j) {
      int rr = m0 + wm * 64 + i * 16 + quad * 4;
      int cc = n0 + wn * 64 + j * 16 + l16;
      if (cc < N) {
#pragma unroll
        for (int r = 0; r < 4; ++r)
          store1(Y + (size_t)(rr + r) * N + cc, acc[i][j][r]);
      }
    }
}

// ---------------------------------------------------------------------------
// Depthwise causal conv (K=4) + silu — vectorized x8 (ushort8), cvt_pk out.
// ---------------------------------------------------------------------------
__global__ __launch_bounds__(256) void conv_silu_v8(const unsigned short* __restrict__ X,
                                                    const float* __restrict__ Wc,
                                                    unsigned short* __restrict__ Y,
                                                    int C, int total8) {
  int i8 = blockIdx.x * 256 + threadIdx.x;
  if (i8 >= total8) return;
  int idx = i8 * 8;
  int c = idx % C;
  int m = idx / C;
  int t = m & 1023;
  u16x8 x0 = *(const u16x8*)(X + idx);
  u16x8 x1 = (u16x8)(unsigned short)0;
  u16x8 x2 = x1, x3 = x1;
  if (t >= 1) x1 = *(const u16x8*)(X + idx - C);
  if (t >= 2) x2 = *(const u16x8*)(X + idx - 2 * C);
  if (t >= 3) x3 = *(const u16x8*)(X + idx - 3 * C);
  float r[8];
#pragma unroll
  for (int e = 0; e < 8; ++e) {
    float4 w4 = *(const float4*)(Wc + (size_t)(c + e) * 4);
    float acc = w4.w * bf2f(x0[e]);
    acc = fmaf(w4.z, bf2f(x1[e]), acc);
    acc = fmaf(w4.y, bf2f(x2[e]), acc);
    acc = fmaf(w4.x, bf2f(x3[e]), acc);
    r[e] = acc * sigmoidf(acc);
  }
  *(uint4*)(Y + idx) = make_uint4(f2bf_pk(r[0], r[1]), f2bf_pk(r[2], r[3]),
                                  f2bf_pk(r[4], r[5]), f2bf_pk(r[6], r[7]));
}

// ---------------------------------------------------------------------------
// l2norm rows of 128 (bf16, in-place) — R6-validated.
// ---------------------------------------------------------------------------
__global__ __launch_bounds__(256) void l2norm_bf16(unsigned short* __restrict__ X,
                                                   int rows, float post) {
  int row = blockIdx.x * 4 + (threadIdx.x >> 6);
  int lane = threadIdx.x & 63;
  if (row >= rows) return;
  unsigned short* p = X + (size_t)row * 128;
  float a = bf2f(p[lane]), b = bf2f(p[lane + 64]);
  float ss = fmaf(a, a, b * b);
#pragma unroll
  for (int m = 32; m; m >>= 1) ss += __shfl_xor(ss, m);
  float sc = rsqrtf(ss + 1e-6f) * post;
  p[lane] = f2bf(a * sc);
  p[lane + 64] = f2bf(b * sc);
}

// ---------------------------------------------------------------------------
// decay in-place (R6-validated).
// ---------------------------------------------------------------------------
__global__ __launch_bounds__(256) void decay_ip(float* __restrict__ G,
                                                const float* __restrict__ alog,
                                                const float* __restrict__ dtb,
                                                int total) {
  int idx = blockIdx.x * 256 + threadIdx.x;
  if (idx >= total) return;
  int n = idx & 2047;
  float A = expf(alog[n >> 7]);
  float x = G[idx] + dtb[n];
  G[idx] = expf(-A * softplusf(x));
}

__global__ __launch_bounds__(256) void sigmoid_ip(float* __restrict__ G, int total) {
  int idx = blockIdx.x * 256 + threadIdx.x;
  if (idx < total) G[idx] = sigmoidf(G[idx]);
}

// ---------------------------------------------------------------------------
// Recurrent scan v8 — 2 columns/wave (R14 structure), prefetch depth 3:
// 4 named Pref2 buffers, x4-unrolled loop, tail loads clamped to t=1023.
// 512 blocks x 256 thr = 2048 waves = 2 waves/SIMD.
// Ladder (R11-validated): xor1(0xB1), xor2(0x4E), half_mirror(0x141),
// mirror(0x140), bcast15(0x142), bcast31(0x143) -> lane 63 total;
// u via readlane(63); o stored as float2 from lane 63.
// ---------------------------------------------------------------------------
template <int CTRL>
__device__ __forceinline__ float dppadd(float x) {
  int y = __builtin_amdgcn_update_dpp(0, __float_as_int(x), CTRL, 0xF, 0xF, true);
  return x + __int_as_float(y);
}
__device__ __forceinline__ float red64_l63(float x) {
  x = dppadd<0xB1>(x);
  x = dppadd<0x4E>(x);
  x = dppadd<0x141>(x);
  x = dppadd<0x140>(x);
  x = dppadd<0x142>(x);
  x = dppadd<0x143>(x);
  return x;  // lane 63 holds the 64-lane total
}
__device__ __forceinline__ float rdl63(float x) {
  return __int_as_float(__builtin_amdgcn_readlane(__float_as_int(x), 63));
}

struct Pref2 {
  ushort2 k[4];   // k[j] at d0, d0+1 (shared across both columns)
  ushort2 q;      // q at d0, d0+1
  float2 d;       // dec at d0, d0+1
  float4 beta;    // 4 micro-steps
  ushort2 v[4];   // v[j] at colA, colA+1
};

__global__ __launch_bounds__(256) void scan_kernel8(
    const unsigned short* __restrict__ Qn, const unsigned short* __restrict__ Kn,
    const unsigned short* __restrict__ Vb, const float* __restrict__ Dec,
    const float* __restrict__ BetaS, const float* __restrict__ ml,
    const float* __restrict__ alog, const float* __restrict__ dtb,
    float* __restrict__ O) {
  // Bijective XCD-clustering for 512 blocks: all 16 cq-blocks of one (b,h)
  // share orig%8 -> one XCD's L2.
  const int orig = blockIdx.x;       // 0..511
  const int xcd = orig & 7;
  const int rr = orig >> 3;          // 0..63
  const int bh = xcd * 4 + (rr & 3); // 0..31
  const int cq = rr >> 2;            // 0..15
  const int h = bh & 15;
  const int b = bh >> 4;
  const int wave = threadIdx.x >> 6; // 0..3
  const int lane = threadIdx.x & 63;
  const int colA = cq * 8 + wave * 2;  // even; wave owns columns colA, colA+1
  const int d0 = lane * 2;

  const float A = expf(alog[h]);
  const float df0 = expf(-A * softplusf(-10000.f + dtb[h * 128 + d0]));
  const float df1 = expf(-A * softplusf(-10000.f + dtb[h * 128 + d0 + 1]));

  float wj[4];
  {
    float l0 = ml[h * 4 + 0], l1 = ml[h * 4 + 1];
    float l2 = ml[h * 4 + 2], l3 = ml[h * 4 + 3];
    float mx = fmaxf(fmaxf(l0, l1), fmaxf(l2, l3));
    float e0 = expf(l0 - mx), e1 = expf(l1 - mx);
    float e2 = expf(l2 - mx), e3 = expf(l3 - mx);
    float inv = 1.f / (e0 + e1 + e2 + e3);
    wj[0] = e0 * inv; wj[1] = e1 * inv; wj[2] = e2 * inv; wj[3] = e3 * inv;
  }

  float SA0 = 0.f, SA1 = 0.f, SB0 = 0.f, SB1 = 0.f;

  // Load step t (clamped to 1023; tail loads are wasted but valid).
  auto LD = [&](int t, Pref2& P) {
    const int tt = (t < 1024) ? t : 1023;
    const size_t base = ((size_t)(b * 1024 + tt) * 16 + h);
    const unsigned short* kp = Kn + base * 512 + d0;
    const unsigned short* vp = Vb + base * 512 + colA;
#pragma unroll
    for (int j = 0; j < 4; ++j) {
      P.k[j] = *(const ushort2*)(kp + j * 128);
      P.v[j] = *(const ushort2*)(vp + j * 128);
    }
    P.q = *(const ushort2*)(Qn + base * 128 + d0);
    P.d = *(const float2*)(Dec + base * 128 + d0);
    P.beta = *(const float4*)(BetaS + base * 4);
  };

  auto STEP = [&](const Pref2& P, int t) {
    const float qf0 = bf2f(P.q.x), qf1 = bf2f(P.q.y);
    float oA = 0.f, oB = 0.f;
    const float bc[4] = {P.beta.x, P.beta.y, P.beta.z, P.beta.w};
#pragma unroll
    for (int j = 0; j < 4; ++j) {
      const float kf0 = bf2f(P.k[j].x), kf1 = bf2f(P.k[j].y);
      const float dd0 = (j == 0) ? P.d.x : df0;
      const float dd1 = (j == 0) ? P.d.y : df1;
      SA0 *= dd0; SA1 *= dd1;
      SB0 *= dd0; SB1 *= dd1;
      float pA = fmaf(kf0, SA0, kf1 * SA1);
      float pB = fmaf(kf0, SB0, kf1 * SB1);
      pA = red64_l63(pA);       // two independent ladders -> ILP
      pB = red64_l63(pB);
      const float uA = rdl63(pA);
      const float uB = rdl63(pB);
      const float ccA = bc[j] * (bf2f(P.v[j].x) - uA);
      const float ccB = bc[j] * (bf2f(P.v[j].y) - uB);
      SA0 = fmaf(ccA, kf0, SA0); SA1 = fmaf(ccA, kf1, SA1);
      SB0 = fmaf(ccB, kf0, SB0); SB1 = fmaf(ccB, kf1, SB1);
      oA = fmaf(wj[j], fmaf(qf0, SA0, qf1 * SA1), oA);
      oB = fmaf(wj[j], fmaf(qf0, SB0, qf1 * SB1), oB);
    }
    oA = red64_l63(oA);
    oB = red64_l63(oB);
    if (lane == 63) {
      const size_t base = ((size_t)(b * 1024 + t) * 16 + h);
      *(float2*)(O + base * 128 + colA) = make_float2(oA, oB);
    }
  };

  // depth-3 prefetch ring over 4 named buffers (no runtime indexing).
  Pref2 PA, PB, PC, PD;
  LD(0, PA);
  LD(1, PB);
  LD(2, PC);
  for (int t = 0; t < 1024; t += 4) {
    LD(t + 3, PD); STEP(PA, t);
    LD(t + 4, PA); STEP(PB, t + 1);
    LD(t + 5, PB); STEP(PC, t + 2);
    LD(t + 6, PC); STEP(PD, t + 3);
  }
}

// ---------------------------------------------------------------------------
// RMS-norm * o_norm_w * sigmoid(gate + g2_b), in-place on O(f32) — R6-validated.
// ---------------------------------------------------------------------------
__global__ __launch_bounds__(256) void norm_gate(float* __restrict__ O,
                                                 const unsigned short* __restrict__ G,
                                                 const float* __restrict__ g2b,
                                                 const float* __restrict__ onw,
                                                 int rows) {
  int row = blockIdx.x * 4 + (threadIdx.x >> 6);
  int lane = threadIdx.x & 63;
  if (row >= rows) return;
  float* p = O + (size_t)row * 128;
  int m = row >> 4, h = row & 15;
  const unsigned short* gp = G + (size_t)m * 2048 + h * 128;
  const float* gb = g2b + h * 128;
  float a = p[lane], bv = p[lane + 64];
  float ss = fmaf(a, a, bv * bv);
#pragma unroll
  for (int k = 32; k; k >>= 1) ss += __shfl_xor(ss, k);
  float sc = rsqrtf(ss * (1.f / 128.f) + 1e-5f);
  float ga = sigmoidf(bf2f(gp[lane]) + gb[lane]);
  float gbv = sigmoidf(bf2f(gp[lane + 64]) + gb[lane + 64]);
  p[lane] = a * sc * onw[lane] * ga;
  p[lane + 64] = bv * sc * onw[lane + 64] * gbv;
}

// ---------------------------------------------------------------------------
extern "C" void kernel_launch(void* const* d_in, const int* in_sizes, int n_in,
                              void* d_out, int out_size, void* d_ws, size_t ws_size,
                              hipStream_t stream) {
  const float* x    = (const float*)d_in[0];
  const float* qw   = (const float*)d_in[1];
  const float* kw   = (const float*)d_in[2];
  const float* vw   = (const float*)d_in[3];
  const float* qcw  = (const float*)d_in[4];
  const float* kcw  = (const float*)d_in[5];
  const float* vcw  = (const float*)d_in[6];
  const float* f1w  = (const float*)d_in[7];
  const float* f2w  = (const float*)d_in[8];
  const float* bw   = (const float*)d_in[9];
  const float* ml   = (const float*)d_in[10];
  const float* alog = (const float*)d_in[11];
  const float* dtb  = (const float*)d_in[12];
  const float* g1w  = (const float*)d_in[13];
  const float* g2w  = (const float*)d_in[14];
  const float* g2b  = (const float*)d_in[15];
  const float* onw  = (const float*)d_in[16];
  const float* ow   = (const float*)d_in[17];
  float* out = (float*)d_out;  // fp32 output

  // workspace carve — peak 120 MiB (R13-validated layout).
  char* w8 = (char*)d_ws;
  unsigned short* P    = (unsigned short*)(w8);               // [0, 32M)
  float*          dec  = (float*)(w8);                        // [0, 16M)
  unsigned short* gate = (unsigned short*)(w8 + 16777216);    // 8 MB
  float*          beta = (float*)(w8 + 25165824);             // 512 KB
  float*          g1t  = (float*)(w8 + 25690112);             // 1 MB
  unsigned short* Kc   = (unsigned short*)(w8 + 33554432);    // 32 MB
  unsigned short* Vc   = (unsigned short*)(w8 + 67108864);    // 32 MB
  unsigned short* wbig = (unsigned short*)(w8 + 67108864);    // kwbf/vwbf (32 MB)
  unsigned short* Qc   = (unsigned short*)(w8 + 100663296);   // 8 MB
  unsigned short* xbf  = (unsigned short*)(w8 + 109051904);   // 8 MB
  unsigned short* qwbf = (unsigned short*)(w8 + 117440512);   // 8 MB (ends 120MiB)
  float*          o    = (float*)(w8 + 109051904);            // 16 MB (scan out)
  unsigned short* owbf = (unsigned short*)(w8);               // 8 MB (post-scan)
  unsigned short* obf  = (unsigned short*)(w8 + 8388608);     // 8 MB (post-scan)
  (void)ws_size;

  const int M = 2048;
  dim3 blk(256);

  // ---- convert x once (used by K/V/Q big GEMMs) ----
  cvt_bf16_v8<<<2048, blk, 0, stream>>>(x, xbf, 524288);

  // ---- phase 1: big projections (bf16 MFMA + gload_lds) + conv ----
  cvt_bf16_v8<<<8192, blk, 0, stream>>>(kw, wbig, 2097152);
  gemm_bf16<unsigned short><<<dim3(64, 16), blk, 0, stream>>>(xbf, wbig, P, M, 8192, 2048);
  conv_silu_v8<<<8192, blk, 0, stream>>>(P, kcw, Kc, 8192, 2097152);
  cvt_bf16_v8<<<8192, blk, 0, stream>>>(vw, wbig, 2097152);
  gemm_bf16<unsigned short><<<dim3(64, 16), blk, 0, stream>>>(xbf, wbig, P, M, 8192, 2048);
  conv_silu_v8<<<8192, blk, 0, stream>>>(P, vcw, Vc, 8192, 2097152);
  cvt_bf16_v8<<<2048, blk, 0, stream>>>(qw, qwbf, 524288);
  gemm_bf16<unsigned short><<<dim3(16, 16), blk, 0, stream>>>(xbf, qwbf, P, M, 2048, 2048);
  conv_silu_v8<<<2048, blk, 0, stream>>>(P, qcw, Qc, 2048, 524288);

  // ---- phase 2: small projections (f32 path; P region now dead) ----
  gemm_mfma<float><<<dim3(1, 16), blk, 0, stream>>>(x, f1w, g1t, M, 128, 2048);
  gemm_mfma<float><<<dim3(16, 16), blk, 0, stream>>>(g1t, f2w, dec, M, 2048, 128);
  decay_ip<<<16384, blk, 0, stream>>>(dec, alog, dtb, 4194304);

  gemm_mfma<float><<<dim3(1, 16), blk, 0, stream>>>(x, bw, beta, M, 64, 2048);
  sigmoid_ip<<<512, blk, 0, stream>>>(beta, 131072);

  gemm_mfma<float><<<dim3(1, 16), blk, 0, stream>>>(x, g1w, g1t, M, 128, 2048);
  gemm_mfma<unsigned short><<<dim3(16, 16), blk, 0, stream>>>(g1t, g2w, gate, M, 2048, 128);

  // ---- l2 norms (in-place bf16) ----
  l2norm_bf16<<<8192, blk, 0, stream>>>(Qc, 32768, 0.08838834764831845f);
  l2norm_bf16<<<32768, blk, 0, stream>>>(Kc, 131072, 1.0f);

  // ---- recurrent scan (2 cols/wave, depth-3 prefetch) ----
  scan_kernel8<<<512, dim3(256), 0, stream>>>(Qc, Kc, Vc, dec, beta, ml, alog, dtb, o);

  // ---- RMS-norm + gate ----
  norm_gate<<<8192, blk, 0, stream>>>(o, gate, g2b, onw, 32768);

  // ---- final projection (bf16 path) -> fp32 out ----
  cvt_bf16_v8<<<2048, blk, 0, stream>>>(o, obf, 524288);
  cvt_bf16_v8<<<2048, blk, 0, stream>>>(ow, owbf, 524288);
  gemm_bf16<float><<<dim3(16, 16), blk, 0, stream>>>(obf, owbf, out, M, 2048, 2048);
}